// Round 10
// baseline (82.878 us; speedup 1.0000x reference)
//
#include <hip/hip_runtime.h>
#include <hip/hip_bf16.h>
#include <stdint.h>
#include <stddef.h>

#define NSEQ  4096
#define DM    1024
#define NHEAD 16
#define DHEAD 64
#define WIN   64

using short8 = __attribute__((ext_vector_type(8))) short;
using f32x4  = __attribute__((ext_vector_type(4))) float;

#define GLOBAL_AS __attribute__((address_space(1)))
#define LDS_AS    __attribute__((address_space(3)))

__device__ __forceinline__ unsigned short f2bf(float f) {
  union { float f; unsigned int u; } v; v.f = f;
  unsigned int r = v.u + 0x7FFFu + ((v.u >> 16) & 1u);
  return (unsigned short)(r >> 16);
}

__device__ __forceinline__ void gload_lds16(void* lds, const void* g) {
  __builtin_amdgcn_global_load_lds((const GLOBAL_AS unsigned int*)g,
                                   (LDS_AS unsigned int*)lds, 16, 0, 0);
}

// ---------------- fused fp32 -> bf16 conversion (x | w_qkv | w_out) --------
#define NX4 1048576
#define NW4 786432
__global__ void cvt_all(const float* __restrict__ x,
                        const float* __restrict__ wqkv,
                        const float* __restrict__ wout,
                        unsigned short* __restrict__ dst) {
  int i = blockIdx.x * blockDim.x + threadIdx.x;   // group of 4 floats
  float4 f;
  if (i < NX4)            f = ((const float4*)x)[i];
  else if (i < NX4 + NW4) f = ((const float4*)wqkv)[i - NX4];
  else                    f = ((const float4*)wout)[i - (NX4 + NW4)];
  ushort4 o;
  o.x = f2bf(f.x); o.y = f2bf(f.y); o.z = f2bf(f.z); o.w = f2bf(f.w);
  ((ushort4*)dst)[i] = o;
}

// ============ QKV GEMM: 256x192, BK=64, frag-double-buffered pipeline ======
// A[4096,1024], B[3072,1024] bf16 K-major. Grid 256 (1/CU). 8 waves 2Mx4N,
// per-wave C = 128x48 (acc[8][3]). LDS 112 KB, 2 K-tile bufs, 16x32 subtiles
// with st_16x32 XOR swizzle (pre-swizzled global source, swizzled read).
// NEW: ds_reads for phase p+1 issued BEFORE phase p's MFMA (register frag
// double-buffer) -> LDS latency hides under MFMA; ONE barrier per K-tile.
// Phases: p0=(qm0,qk0) p1=(qm1,qk0) p2=(qm0,qk1) p3=(qm1,qk1).
// Staging: p0: {A(j+1)x4, Bk1(j+1)x2}; p3 post-barrier: Bk0(j+2)x2.
// Ledger: at j.p3 after stage, outstanding = 6 (j.p0) + 2 (j.p3);
// vmcnt(2) drains {A,Bk1,Bk0}(j+1) exactly. lgkmcnt(0) before the barrier
// guarantees all waves' buf-reads done before post-barrier overwrites.
__global__ __launch_bounds__(512, 1)
void gemm_qkv(const unsigned short* __restrict__ A,
              const unsigned short* __restrict__ B,
              const float* __restrict__ bias,
              unsigned short* __restrict__ qo,
              unsigned short* __restrict__ ko,
              unsigned short* __restrict__ vo) {
  __shared__ short lds[57344];   // 112 KB: buf b at b*28672 {A:16384|B:12288}

  const int bm = blockIdx.x >> 4;    // M/256 = 16
  const int bn = blockIdx.x & 15;    // N/192 = 16
  const int m0 = bm << 8, n0 = bn * 192;
  const int tid = threadIdx.x, w = tid >> 6, l = tid & 63;
  const int wr = w >> 2, wc = w & 3;
  const int l15 = l & 15, l4 = l >> 4;
  const int srow = l >> 2;
  const int skel = ((l & 3) << 3) ^ ((l >= 32) << 4);          // inv-swz global k
  const int roff = l15 * 32 + ((l4 * 8) ^ ((l15 >= 8) * 16));  // swz read off

  f32x4 acc[8][3] = {};

  auto stageA = [&](int j, int qm) {
    const int base = (j & 1) * 28672 + qm * 8192;
#pragma unroll
    for (int r = 0; r < 2; ++r) {
      const int c = r * 8 + w;
      gload_lds16(&lds[base + c * 512 + l * 8],
                  A + (size_t)(m0 + qm * 128 + (c >> 1) * 16 + srow) * 1024
                    + (j << 6) + (c & 1) * 32 + skel);
    }
  };
  auto stageB = [&](int j, int qk) {
    const int base = (j & 1) * 28672 + 16384 + qk * 6144;
    {
      const int c = w;               // subtiles 0..7
      gload_lds16(&lds[base + c * 512 + l * 8],
                  B + (size_t)(n0 + c * 16 + srow) * 1024
                    + (j << 6) + qk * 32 + skel);
    }
    {
      const int c = 8 + (w & 3);     // subtiles 8..11 (x2 coverage)
      gload_lds16(&lds[base + c * 512 + l * 8],
                  B + (size_t)(n0 + c * 16 + srow) * 1024
                    + (j << 6) + qk * 32 + skel);
    }
  };

  // fragment load for phase (qm,qk) of tile in `buf`
  auto ldfrag = [&](short8* af, short8* bf, int buf, int qm, int qk) {
    const short* Ah = &lds[buf + wr * 8192];
    const short* Bh = &lds[buf + 16384 + qk * 6144];
#pragma unroll
    for (int i = 0; i < 4; ++i)
      af[i] = *(const short8*)&Ah[(qm * 4 + i) * 1024 + qk * 512 + roff];
#pragma unroll
    for (int ni = 0; ni < 3; ++ni)
      bf[ni] = *(const short8*)&Bh[(wc * 3 + ni) * 512 + roff];
  };
  auto domfma = [&](const short8* af, const short8* bf, int qm) {
    __builtin_amdgcn_s_setprio(1);
#pragma unroll
    for (int i = 0; i < 4; ++i)
#pragma unroll
      for (int ni = 0; ni < 3; ++ni)
        acc[qm * 4 + i][ni] = __builtin_amdgcn_mfma_f32_16x16x32_bf16(
            af[i], bf[ni], acc[qm * 4 + i][ni], 0, 0, 0);
    __builtin_amdgcn_s_setprio(0);
  };

  // prologue: A(0), Bk1(0), Bk0(0), Bk0(1); vmcnt(2) leaves Bk0(1) in flight
  stageA(0, 0); stageA(0, 1); stageB(0, 1); stageB(0, 0); stageB(1, 0);
  asm volatile("s_waitcnt vmcnt(2)" ::: "memory");
  __builtin_amdgcn_s_barrier();

  short8 afA[4], bfA[3], afB[4], bfB[3];
  ldfrag(afA, bfA, 0, 0, 0);          // p0 of tile 0

  const int NT = 16;   // 1024 / 64
  for (int j = 0; j < NT; ++j) {
    const int buf = (j & 1) * 28672;
    // ---- p0: stage next tile's A + Bk1; prefetch p1; MFMA p0 ----
    if (j + 1 < NT) { stageA(j + 1, 0); stageA(j + 1, 1); stageB(j + 1, 1); }
    ldfrag(afB, bfB, buf, 1, 0);
    domfma(afA, bfA, 0);
    // ---- p1: prefetch p2; MFMA p1 ----
    ldfrag(afA, bfA, buf, 0, 1);
    domfma(afB, bfB, 1);
    // ---- p2: prefetch p3; MFMA p2 ----
    ldfrag(afB, bfB, buf, 1, 1);
    domfma(afA, bfA, 0);
    // ---- p3: publish barrier; stage Bk0(j+2); prefetch p0(j+1); MFMA p3 ----
    asm volatile("s_waitcnt lgkmcnt(0)" ::: "memory");  // all buf-reads done
    __builtin_amdgcn_s_barrier();
    if (j + 2 < NT) stageB(j + 2, 0);
    if (j + 1 < NT) {
      if (j + 2 < NT) asm volatile("s_waitcnt vmcnt(2)" ::: "memory");
      else            asm volatile("s_waitcnt vmcnt(0)" ::: "memory");
      ldfrag(afA, bfA, buf ^ 28672, 0, 0);
    }
    domfma(afB, bfB, 1);
  }

  // epilogue: scatter to Q (scaled), K, V^T
#pragma unroll
  for (int ni = 0; ni < 3; ++ni) {
    const int n  = n0 + wc * 48 + ni * 16 + l15;
    const float bv = bias[n];
    const int region = n >> 10;   // uniform per 16-col fragment
#pragma unroll
    for (int mi = 0; mi < 8; ++mi) {
      const int mb = m0 + wr * 128 + mi * 16 + l4 * 4;
      if (region == 0) {
        const int h = (n >> 6) & 15, d = n & 63;
#pragma unroll
        for (int r = 0; r < 4; ++r)
          qo[((size_t)(h * NSEQ + mb + r)) * DHEAD + d] =
              f2bf((acc[mi][ni][r] + bv) * 0.125f);
      } else if (region == 1) {
        const int nn = n - 1024;
        const int h = nn >> 6, d = nn & 63;
#pragma unroll
        for (int r = 0; r < 4; ++r)
          ko[((size_t)(h * NSEQ + mb + r)) * DHEAD + d] =
              f2bf(acc[mi][ni][r] + bv);
      } else {
        const int nn = n - 2048;    // = h*64 + d
        ushort4 pk;
        pk.x = f2bf(acc[mi][ni][0] + bv);
        pk.y = f2bf(acc[mi][ni][1] + bv);
        pk.z = f2bf(acc[mi][ni][2] + bv);
        pk.w = f2bf(acc[mi][ni][3] + bv);
        *(ushort4*)&vo[(size_t)nn * NSEQ + mb] = pk;   // V^T: [h*64+d][m]
      }
    }
  }
}

// ====== out-proj GEMM: 64x64 tile, BK=64, 2-buf, m97 TLP regime ============
// (unchanged from round 9)
__global__ __launch_bounds__(256)
void gemm_op(const unsigned short* __restrict__ A,
             const unsigned short* __restrict__ B,
             const float* __restrict__ bias,
             float* __restrict__ Cf) {
  __shared__ short lds[2][8192];   // 16 KB/buf: A 4096 | B 4096 shorts

  const int bm = blockIdx.x >> 4;   // 4096/64 = 64
  const int bn = blockIdx.x & 15;   // 1024/64 = 16
  const int m0 = bm << 6, n0 = bn << 6;
  const int tid = threadIdx.x, w = tid >> 6, l = tid & 63;
  const int wr = w >> 1, wc = w & 1;
  const int l15 = l & 15, l4 = l >> 4;
  const int srow = l >> 2;
  const int skel = ((l & 3) << 3) ^ ((l >= 32) << 4);
  const int roff = l15 * 32 + ((l4 * 8) ^ ((l15 >= 8) * 16));

  f32x4 acc[2][2] = {};
  const int NT = 16;

  auto stage = [&](int t) {
    const int buf = t & 1;
    const int kb  = t << 6;
#pragma unroll
    for (int r = 0; r < 2; ++r) {
      const int c = r * 4 + w;
      gload_lds16(&lds[buf][c * 512 + l * 8],
                  A + (size_t)(m0 + (c >> 1) * 16 + srow) * 1024
                    + kb + (c & 1) * 32 + skel);
      gload_lds16(&lds[buf][4096 + c * 512 + l * 8],
                  B + (size_t)(n0 + (c >> 1) * 16 + srow) * 1024
                    + kb + (c & 1) * 32 + skel);
    }
  };

  stage(0);
  for (int t = 0; t < NT; ++t) {
    __syncthreads();                    // drains vmcnt -> stage(t) visible
    if (t + 1 < NT) stage(t + 1);       // writes other buf (WAR-safe)
    const short* Ab = &lds[t & 1][0];
    const short* Bb = &lds[t & 1][4096];
    short8 af[2][2], bf[2][2];
#pragma unroll
    for (int mi = 0; mi < 2; ++mi)
#pragma unroll
      for (int kk = 0; kk < 2; ++kk)
        af[mi][kk] = *(const short8*)&Ab[((wr * 2 + mi) * 2 + kk) * 512 + roff];
#pragma unroll
    for (int ni = 0; ni < 2; ++ni)
#pragma unroll
      for (int kk = 0; kk < 2; ++kk)
        bf[ni][kk] = *(const short8*)&Bb[((wc * 2 + ni) * 2 + kk) * 512 + roff];
    __builtin_amdgcn_s_setprio(1);
#pragma unroll
    for (int kk = 0; kk < 2; ++kk)
#pragma unroll
      for (int mi = 0; mi < 2; ++mi)
#pragma unroll
        for (int ni = 0; ni < 2; ++ni)
          acc[mi][ni] = __builtin_amdgcn_mfma_f32_16x16x32_bf16(
              af[mi][kk], bf[ni][kk], acc[mi][ni], 0, 0, 0);
    __builtin_amdgcn_s_setprio(0);
  }

#pragma unroll
  for (int ni = 0; ni < 2; ++ni) {
    const int n  = n0 + wc * 32 + ni * 16 + l15;
    const float bv = bias[n];
#pragma unroll
    for (int mi = 0; mi < 2; ++mi) {
      const int mb = m0 + wr * 32 + mi * 16 + l4 * 4;
#pragma unroll
      for (int r = 0; r < 4; ++r)
        Cf[(size_t)(mb + r) * DM + n] = acc[mi][ni][r] + bv;
    }
  }
}

// ---------------- windowed causal attention: 6-tile window trim ------------
// (unchanged from round 9)
__global__ __launch_bounds__(256)
void attn_kernel(const unsigned short* __restrict__ Qb,
                 const unsigned short* __restrict__ Kb,
                 const unsigned short* __restrict__ Vt,
                 unsigned short* __restrict__ att) {
  __shared__ short Pl[4][16][136];
  const int h  = blockIdx.x >> 6;
  const int q0 = (blockIdx.x & 63) << 6;
  const int w  = threadIdx.x >> 6;
  const int l  = threadIdx.x & 63;
  const int l15 = l & 15, l4 = l >> 4;
  const int qw = q0 + w * 16;
  const int tb = w & ~1;           // base key tile (even), tiles tb..tb+5

  const unsigned short* Qh = Qb + (size_t)h * NSEQ * DHEAD;
  const unsigned short* Kh = Kb + (size_t)h * NSEQ * DHEAD;
  const unsigned short* Vh = Vt + (size_t)h * DHEAD * NSEQ;

  short8 aq[2];
  {
    const int qrow = qw + l15;
    aq[0] = *(const short8*)&Qh[(size_t)qrow * DHEAD + l4 * 8];
    aq[1] = *(const short8*)&Qh[(size_t)qrow * DHEAD + 32 + l4 * 8];
  }

  f32x4 s[6] = {};
#pragma unroll
  for (int tt = 0; tt < 6; ++tt) {
    int j  = q0 - 64 + (tb + tt) * 16 + l15;
    int jc = j < 0 ? 0 : j;
    short8 b0 = *(const short8*)&Kh[(size_t)jc * DHEAD + l4 * 8];
    short8 b1 = *(const short8*)&Kh[(size_t)jc * DHEAD + 32 + l4 * 8];
    s[tt] = __builtin_amdgcn_mfma_f32_16x16x32_bf16(aq[0], b0, s[tt], 0, 0, 0);
    s[tt] = __builtin_amdgcn_mfma_f32_16x16x32_bf16(aq[1], b1, s[tt], 0, 0, 0);
  }

  float rmax[4] = {-3e38f, -3e38f, -3e38f, -3e38f};
#pragma unroll
  for (int tt = 0; tt < 6; ++tt)
#pragma unroll
    for (int r = 0; r < 4; ++r) {
      const int i = qw + l4 * 4 + r;
      const int j = q0 - 64 + (tb + tt) * 16 + l15;
      const int diff = i - j;
      float sv = (j >= 0 && diff >= 0 && diff < WIN) ? s[tt][r] : -3e38f;
      s[tt][r] = sv;
      rmax[r] = fmaxf(rmax[r], sv);
    }
#pragma unroll
  for (int r = 0; r < 4; ++r)
#pragma unroll
    for (int m = 1; m < 16; m <<= 1)
      rmax[r] = fmaxf(rmax[r], __shfl_xor(rmax[r], m, 64));

  float rsum[4] = {0.f, 0.f, 0.f, 0.f};
#pragma unroll
  for (int tt = 0; tt < 6; ++tt)
#pragma unroll
    for (int r = 0; r < 4; ++r) {
      float p = __expf(s[tt][r] - rmax[r]);
      s[tt][r] = p;
      rsum[r] += p;
    }
#pragma unroll
  for (int r = 0; r < 4; ++r)
#pragma unroll
    for (int m = 1; m < 16; m <<= 1)
      rsum[r] += __shfl_xor(rsum[r], m, 64);

#pragma unroll
  for (int tt = 0; tt < 6; ++tt)
#pragma unroll
    for (int r = 0; r < 4; ++r)
      Pl[w][l4 * 4 + r][(tb + tt) * 16 + l15] = (short)f2bf(s[tt][r]);

  f32x4 o[4] = {};
#pragma unroll
  for (int kq = 0; kq < 3; ++kq) {
    const int ks = (w >> 1) + kq;
    short8 ap = *(const short8*)&Pl[w][l15][ks * 32 + l4 * 8];
    int jg = q0 - 64 + ks * 32 + l4 * 8;
    if (jg < 0) jg = 0;                       // P==0 there
#pragma unroll
    for (int dt = 0; dt < 4; ++dt) {
      const int d = dt * 16 + l15;
      short8 bv = *(const short8*)&Vh[(size_t)d * NSEQ + jg];
      o[dt] = __builtin_amdgcn_mfma_f32_16x16x32_bf16(ap, bv, o[dt], 0, 0, 0);
    }
  }

#pragma unroll
  for (int r = 0; r < 4; ++r) {
    const float rinv = 1.0f / rsum[r];
    const int m = qw + l4 * 4 + r;
#pragma unroll
    for (int dt = 0; dt < 4; ++dt)
      att[(size_t)m * DM + h * DHEAD + dt * 16 + l15] = f2bf(o[dt][r] * rinv);
  }
}

// ---------------- launch ----------------
extern "C" void kernel_launch(void* const* d_in, const int* in_sizes, int n_in,
                              void* d_out, int out_size, void* d_ws, size_t ws_size,
                              hipStream_t stream) {
  const float* x    = (const float*)d_in[0];
  const float* wqkv = (const float*)d_in[1];
  const float* bqkv = (const float*)d_in[2];
  const float* wout = (const float*)d_in[3];
  const float* bout = (const float*)d_in[4];
  float* out = (float*)d_out;

  unsigned short* ws = (unsigned short*)d_ws;
  unsigned short* xb    = ws;
  unsigned short* wqkvb = xb    + (size_t)NSEQ * DM;
  unsigned short* woutb = wqkvb + (size_t)3 * DM * DM;
  unsigned short* qb    = woutb + (size_t)DM * DM;
  unsigned short* kb    = qb    + (size_t)NSEQ * DM;
  unsigned short* vtb   = kb    + (size_t)NSEQ * DM;
  unsigned short* attb  = vtb   + (size_t)NSEQ * DM;

  cvt_all<<<8192, 256, 0, stream>>>(x, wqkv, wout, xb);

  gemm_qkv<<<16 * 16, 512, 0, stream>>>(xb, wqkvb, bqkv, qb, kb, vtb);

  attn_kernel<<<NHEAD * (NSEQ / 64), 256, 0, stream>>>(qb, kb, vtb, attb);

  gemm_op<<<64 * 16, 256, 0, stream>>>(attb, woutb, bout, out);
}

// Round 11
// 81.378 us; speedup vs baseline: 1.0184x; 1.0184x over previous
//
#include <hip/hip_runtime.h>
#include <hip/hip_bf16.h>
#include <stdint.h>
#include <stddef.h>

#define NSEQ  4096
#define DM    1024
#define NHEAD 16
#define DHEAD 64
#define WIN   64

using short8 = __attribute__((ext_vector_type(8))) short;
using f32x4  = __attribute__((ext_vector_type(4))) float;

#define GLOBAL_AS __attribute__((address_space(1)))
#define LDS_AS    __attribute__((address_space(3)))

__device__ __forceinline__ unsigned short f2bf(float f) {
  union { float f; unsigned int u; } v; v.f = f;
  unsigned int r = v.u + 0x7FFFu + ((v.u >> 16) & 1u);
  return (unsigned short)(r >> 16);
}

__device__ __forceinline__ void gload_lds16(void* lds, const void* g) {
  __builtin_amdgcn_global_load_lds((const GLOBAL_AS unsigned int*)g,
                                   (LDS_AS unsigned int*)lds, 16, 0, 0);
}

// ---------------- fused fp32 -> bf16 conversion (x | w_qkv | w_out) --------
#define NX4 1048576
#define NW4 786432
__global__ void cvt_all(const float* __restrict__ x,
                        const float* __restrict__ wqkv,
                        const float* __restrict__ wout,
                        unsigned short* __restrict__ dst) {
  int i = blockIdx.x * blockDim.x + threadIdx.x;   // group of 4 floats
  float4 f;
  if (i < NX4)            f = ((const float4*)x)[i];
  else if (i < NX4 + NW4) f = ((const float4*)wqkv)[i - NX4];
  else                    f = ((const float4*)wout)[i - (NX4 + NW4)];
  ushort4 o;
  o.x = f2bf(f.x); o.y = f2bf(f.y); o.z = f2bf(f.z); o.w = f2bf(f.w);
  ((ushort4*)dst)[i] = o;
}

// ============ QKV GEMM: 256x192, BK=64, m201-style 4-phase engine ==========
// Grid 256 (1/CU). 8 waves 2Mx4N, per-wave C = 128x48 (acc[8][3]).
// LDS 112 KB, 2 K-tile bufs, 16x32 subtiles, st_16x32 XOR swizzle
// (pre-swizzled global source, swizzled read).
// Per K-tile j, 4 phases (qm,qk) = (0,0)(1,0)(0,1)(1,1), 12 MFMA each.
// Phase = {ds_reads (7 / 4; B-frags HELD across the qm pair) | 2 stage
// loads | counted vmcnt | barrier | lgkmcnt(0)+sched_barrier | setprio |
// MFMA | setprio | barrier}.
// Stage quarters of tile j+1: Q0=A(qm0)@p0, Q3=B(qk0)@p1, Q1=A(qm1)@p2,
// Q2=B(qk1)@p3 (2 gloads each). In-order vmcnt ledger (4 loads = 2 qtrs):
//   p0: issue Q0(j+1), vmcnt(4) -> Q1(j) drained (publ. at barrier, read p1)
//   p1: issue Q3(j+1), vmcnt(4) -> Q2(j) drained (read p2)
//   p2: issue Q1(j+1), no wait (outstanding 6)
//   p3: issue Q2(j+1), vmcnt(4) -> Q0,Q3(j+1) drained (read next p0)
// Tail (j=NT-1, no staging): p0 vmcnt(2), p1 vmcnt(0).
// WAR: every stage targets a region whose last ds_read was >=2 phases and
// >=2 barriers earlier. Prologue: Q0 Q3 Q1 Q2 of tile 0, vmcnt(4), barrier.
__global__ __launch_bounds__(512, 1)
void gemm_qkv(const unsigned short* __restrict__ A,
              const unsigned short* __restrict__ B,
              const float* __restrict__ bias,
              unsigned short* __restrict__ qo,
              unsigned short* __restrict__ ko,
              unsigned short* __restrict__ vo) {
  __shared__ short lds[57344];   // 112 KB: buf b at b*28672 {A:16384|B:12288}

  const int bm = blockIdx.x >> 4;    // M/256 = 16
  const int bn = blockIdx.x & 15;    // N/192 = 16
  const int m0 = bm << 8, n0 = bn * 192;
  const int tid = threadIdx.x, w = tid >> 6, l = tid & 63;
  const int wr = w >> 2, wc = w & 3;
  const int l15 = l & 15, l4 = l >> 4;
  const int srow = l >> 2;
  const int skel = ((l & 3) << 3) ^ ((l >= 32) << 4);          // inv-swz global k
  const int roff = l15 * 32 + ((l4 * 8) ^ ((l15 >= 8) * 16));  // swz read off

  f32x4 acc[8][3] = {};

  auto stageA = [&](int j, int qm) {   // Q0 (qm=0) / Q1 (qm=1): 2 gloads
    const int base = (j & 1) * 28672 + qm * 8192;
#pragma unroll
    for (int r = 0; r < 2; ++r) {
      const int c = r * 8 + w;
      gload_lds16(&lds[base + c * 512 + l * 8],
                  A + (size_t)(m0 + qm * 128 + (c >> 1) * 16 + srow) * 1024
                    + (j << 6) + (c & 1) * 32 + skel);
    }
  };
  auto stageB = [&](int j, int qk) {   // Q3 (qk=0) / Q2 (qk=1): 2 gloads
    const int base = (j & 1) * 28672 + 16384 + qk * 6144;
    {
      const int c = w;               // subtiles 0..7
      gload_lds16(&lds[base + c * 512 + l * 8],
                  B + (size_t)(n0 + c * 16 + srow) * 1024
                    + (j << 6) + qk * 32 + skel);
    }
    {
      const int c = 8 + (w & 3);     // subtiles 8..11 (x2 coverage)
      gload_lds16(&lds[base + c * 512 + l * 8],
                  B + (size_t)(n0 + c * 16 + srow) * 1024
                    + (j << 6) + qk * 32 + skel);
    }
  };

  auto ldA = [&](short8* af, int buf, int qm, int qk) {
    const short* Ah = &lds[buf + wr * 8192];
#pragma unroll
    for (int i = 0; i < 4; ++i)
      af[i] = *(const short8*)&Ah[(qm * 4 + i) * 1024 + qk * 512 + roff];
  };
  auto ldB = [&](short8* bf, int buf, int qk) {
    const short* Bh = &lds[buf + 16384 + qk * 6144];
#pragma unroll
    for (int ni = 0; ni < 3; ++ni)
      bf[ni] = *(const short8*)&Bh[(wc * 3 + ni) * 512 + roff];
  };
  auto mfma12 = [&](const short8* af, const short8* bf, int qm) {
    __builtin_amdgcn_s_setprio(1);
#pragma unroll
    for (int i = 0; i < 4; ++i)
#pragma unroll
      for (int ni = 0; ni < 3; ++ni)
        acc[qm * 4 + i][ni] = __builtin_amdgcn_mfma_f32_16x16x32_bf16(
            af[i], bf[ni], acc[qm * 4 + i][ni], 0, 0, 0);
    __builtin_amdgcn_s_setprio(0);
  };

  // prologue: Q0(0) Q3(0) Q1(0) Q2(0); vmcnt(4) leaves {Q1,Q2}(0) in flight
  stageA(0, 0); stageB(0, 0); stageA(0, 1); stageB(0, 1);
  asm volatile("s_waitcnt vmcnt(4)" ::: "memory");
  __builtin_amdgcn_s_barrier();

  const int NT = 16;   // 1024 / 64
  short8 af[4], bf[3];
  for (int j = 0; j < NT; ++j) {
    const int buf = (j & 1) * 28672;
    const bool st = (j + 1 < NT);
    // ---- p0 (qm0,qk0) ----
    ldA(af, buf, 0, 0); ldB(bf, buf, 0);
    if (st) { stageA(j + 1, 0);
              asm volatile("s_waitcnt vmcnt(4)" ::: "memory"); }
    else    { asm volatile("s_waitcnt vmcnt(2)" ::: "memory"); }
    __builtin_amdgcn_s_barrier();
    asm volatile("s_waitcnt lgkmcnt(0)" ::: "memory");
    __builtin_amdgcn_sched_barrier(0);
    mfma12(af, bf, 0);
    __builtin_amdgcn_s_barrier();
    // ---- p1 (qm1,qk0) — bf held ----
    ldA(af, buf, 1, 0);
    if (st) { stageB(j + 1, 0);
              asm volatile("s_waitcnt vmcnt(4)" ::: "memory"); }
    else    { asm volatile("s_waitcnt vmcnt(0)" ::: "memory"); }
    __builtin_amdgcn_s_barrier();
    asm volatile("s_waitcnt lgkmcnt(0)" ::: "memory");
    __builtin_amdgcn_sched_barrier(0);
    mfma12(af, bf, 1);
    __builtin_amdgcn_s_barrier();
    // ---- p2 (qm0,qk1) ----
    ldA(af, buf, 0, 1); ldB(bf, buf, 1);
    if (st) stageA(j + 1, 1);
    __builtin_amdgcn_s_barrier();
    asm volatile("s_waitcnt lgkmcnt(0)" ::: "memory");
    __builtin_amdgcn_sched_barrier(0);
    mfma12(af, bf, 0);
    __builtin_amdgcn_s_barrier();
    // ---- p3 (qm1,qk1) — bf held ----
    ldA(af, buf, 1, 1);
    if (st) { stageB(j + 1, 1);
              asm volatile("s_waitcnt vmcnt(4)" ::: "memory"); }
    __builtin_amdgcn_s_barrier();
    asm volatile("s_waitcnt lgkmcnt(0)" ::: "memory");
    __builtin_amdgcn_sched_barrier(0);
    mfma12(af, bf, 1);
    __builtin_amdgcn_s_barrier();
  }

  // epilogue: scatter to Q (scaled), K, V^T
#pragma unroll
  for (int ni = 0; ni < 3; ++ni) {
    const int n  = n0 + wc * 48 + ni * 16 + l15;
    const float bv = bias[n];
    const int region = n >> 10;   // uniform per 16-col fragment
#pragma unroll
    for (int mi = 0; mi < 8; ++mi) {
      const int mb = m0 + wr * 128 + mi * 16 + l4 * 4;
      if (region == 0) {
        const int h = (n >> 6) & 15, d = n & 63;
#pragma unroll
        for (int r = 0; r < 4; ++r)
          qo[((size_t)(h * NSEQ + mb + r)) * DHEAD + d] =
              f2bf((acc[mi][ni][r] + bv) * 0.125f);
      } else if (region == 1) {
        const int nn = n - 1024;
        const int h = nn >> 6, d = nn & 63;
#pragma unroll
        for (int r = 0; r < 4; ++r)
          ko[((size_t)(h * NSEQ + mb + r)) * DHEAD + d] =
              f2bf(acc[mi][ni][r] + bv);
      } else {
        const int nn = n - 2048;    // = h*64 + d
        ushort4 pk;
        pk.x = f2bf(acc[mi][ni][0] + bv);
        pk.y = f2bf(acc[mi][ni][1] + bv);
        pk.z = f2bf(acc[mi][ni][2] + bv);
        pk.w = f2bf(acc[mi][ni][3] + bv);
        *(ushort4*)&vo[(size_t)nn * NSEQ + mb] = pk;   // V^T: [h*64+d][m]
      }
    }
  }
}

// ====== out-proj GEMM: 64x64 tile, BK=64, 2-buf, m97 TLP regime ============
// (unchanged from round 9)
__global__ __launch_bounds__(256)
void gemm_op(const unsigned short* __restrict__ A,
             const unsigned short* __restrict__ B,
             const float* __restrict__ bias,
             float* __restrict__ Cf) {
  __shared__ short lds[2][8192];   // 16 KB/buf: A 4096 | B 4096 shorts

  const int bm = blockIdx.x >> 4;   // 4096/64 = 64
  const int bn = blockIdx.x & 15;   // 1024/64 = 16
  const int m0 = bm << 6, n0 = bn << 6;
  const int tid = threadIdx.x, w = tid >> 6, l = tid & 63;
  const int wr = w >> 1, wc = w & 1;
  const int l15 = l & 15, l4 = l >> 4;
  const int srow = l >> 2;
  const int skel = ((l & 3) << 3) ^ ((l >= 32) << 4);
  const int roff = l15 * 32 + ((l4 * 8) ^ ((l15 >= 8) * 16));

  f32x4 acc[2][2] = {};
  const int NT = 16;

  auto stage = [&](int t) {
    const int buf = t & 1;
    const int kb  = t << 6;
#pragma unroll
    for (int r = 0; r < 2; ++r) {
      const int c = r * 4 + w;
      gload_lds16(&lds[buf][c * 512 + l * 8],
                  A + (size_t)(m0 + (c >> 1) * 16 + srow) * 1024
                    + kb + (c & 1) * 32 + skel);
      gload_lds16(&lds[buf][4096 + c * 512 + l * 8],
                  B + (size_t)(n0 + (c >> 1) * 16 + srow) * 1024
                    + kb + (c & 1) * 32 + skel);
    }
  };

  stage(0);
  for (int t = 0; t < NT; ++t) {
    __syncthreads();                    // drains vmcnt -> stage(t) visible
    if (t + 1 < NT) stage(t + 1);       // writes other buf (WAR-safe)
    const short* Ab = &lds[t & 1][0];
    const short* Bb = &lds[t & 1][4096];
    short8 af[2][2], bf[2][2];
#pragma unroll
    for (int mi = 0; mi < 2; ++mi)
#pragma unroll
      for (int kk = 0; kk < 2; ++kk)
        af[mi][kk] = *(const short8*)&Ab[((wr * 2 + mi) * 2 + kk) * 512 + roff];
#pragma unroll
    for (int ni = 0; ni < 2; ++ni)
#pragma unroll
      for (int kk = 0; kk < 2; ++kk)
        bf[ni][kk] = *(const short8*)&Bb[((wc * 2 + ni) * 2 + kk) * 512 + roff];
    __builtin_amdgcn_s_setprio(1);
#pragma unroll
    for (int kk = 0; kk < 2; ++kk)
#pragma unroll
      for (int mi = 0; mi < 2; ++mi)
#pragma unroll
        for (int ni = 0; ni < 2; ++ni)
          acc[mi][ni] = __builtin_amdgcn_mfma_f32_16x16x32_bf16(
              af[mi][kk], bf[ni][kk], acc[mi][ni], 0, 0, 0);
    __builtin_amdgcn_s_setprio(0);
  }

#pragma unroll
  for (int ni = 0; ni < 2; ++ni) {
    const int n  = n0 + wc * 32 + ni * 16 + l15;
    const float bv = bias[n];
#pragma unroll
    for (int mi = 0; mi < 2; ++mi) {
      const int mb = m0 + wr * 32 + mi * 16 + l4 * 4;
#pragma unroll
      for (int r = 0; r < 4; ++r)
        Cf[(size_t)(mb + r) * DM + n] = acc[mi][ni][r] + bv;
    }
  }
}

// ---------------- windowed causal attention: 6-tile window trim ------------
// (unchanged from round 9)
__global__ __launch_bounds__(256)
void attn_kernel(const unsigned short* __restrict__ Qb,
                 const unsigned short* __restrict__ Kb,
                 const unsigned short* __restrict__ Vt,
                 unsigned short* __restrict__ att) {
  __shared__ short Pl[4][16][136];
  const int h  = blockIdx.x >> 6;
  const int q0 = (blockIdx.x & 63) << 6;
  const int w  = threadIdx.x >> 6;
  const int l  = threadIdx.x & 63;
  const int l15 = l & 15, l4 = l >> 4;
  const int qw = q0 + w * 16;
  const int tb = w & ~1;           // base key tile (even), tiles tb..tb+5

  const unsigned short* Qh = Qb + (size_t)h * NSEQ * DHEAD;
  const unsigned short* Kh = Kb + (size_t)h * NSEQ * DHEAD;
  const unsigned short* Vh = Vt + (size_t)h * DHEAD * NSEQ;

  short8 aq[2];
  {
    const int qrow = qw + l15;
    aq[0] = *(const short8*)&Qh[(size_t)qrow * DHEAD + l4 * 8];
    aq[1] = *(const short8*)&Qh[(size_t)qrow * DHEAD + 32 + l4 * 8];
  }

  f32x4 s[6] = {};
#pragma unroll
  for (int tt = 0; tt < 6; ++tt) {
    int j  = q0 - 64 + (tb + tt) * 16 + l15;
    int jc = j < 0 ? 0 : j;
    short8 b0 = *(const short8*)&Kh[(size_t)jc * DHEAD + l4 * 8];
    short8 b1 = *(const short8*)&Kh[(size_t)jc * DHEAD + 32 + l4 * 8];
    s[tt] = __builtin_amdgcn_mfma_f32_16x16x32_bf16(aq[0], b0, s[tt], 0, 0, 0);
    s[tt] = __builtin_amdgcn_mfma_f32_16x16x32_bf16(aq[1], b1, s[tt], 0, 0, 0);
  }

  float rmax[4] = {-3e38f, -3e38f, -3e38f, -3e38f};
#pragma unroll
  for (int tt = 0; tt < 6; ++tt)
#pragma unroll
    for (int r = 0; r < 4; ++r) {
      const int i = qw + l4 * 4 + r;
      const int j = q0 - 64 + (tb + tt) * 16 + l15;
      const int diff = i - j;
      float sv = (j >= 0 && diff >= 0 && diff < WIN) ? s[tt][r] : -3e38f;
      s[tt][r] = sv;
      rmax[r] = fmaxf(rmax[r], sv);
    }
#pragma unroll
  for (int r = 0; r < 4; ++r)
#pragma unroll
    for (int m = 1; m < 16; m <<= 1)
      rmax[r] = fmaxf(rmax[r], __shfl_xor(rmax[r], m, 64));

  float rsum[4] = {0.f, 0.f, 0.f, 0.f};
#pragma unroll
  for (int tt = 0; tt < 6; ++tt)
#pragma unroll
    for (int r = 0; r < 4; ++r) {
      float p = __expf(s[tt][r] - rmax[r]);
      s[tt][r] = p;
      rsum[r] += p;
    }
#pragma unroll
  for (int r = 0; r < 4; ++r)
#pragma unroll
    for (int m = 1; m < 16; m <<= 1)
      rsum[r] += __shfl_xor(rsum[r], m, 64);

#pragma unroll
  for (int tt = 0; tt < 6; ++tt)
#pragma unroll
    for (int r = 0; r < 4; ++r)
      Pl[w][l4 * 4 + r][(tb + tt) * 16 + l15] = (short)f2bf(s[tt][r]);

  f32x4 o[4] = {};
#pragma unroll
  for (int kq = 0; kq < 3; ++kq) {
    const int ks = (w >> 1) + kq;
    short8 ap = *(const short8*)&Pl[w][l15][ks * 32 + l4 * 8];
    int jg = q0 - 64 + ks * 32 + l4 * 8;
    if (jg < 0) jg = 0;                       // P==0 there
#pragma unroll
    for (int dt = 0; dt < 4; ++dt) {
      const int d = dt * 16 + l15;
      short8 bv = *(const short8*)&Vh[(size_t)d * NSEQ + jg];
      o[dt] = __builtin_amdgcn_mfma_f32_16x16x32_bf16(ap, bv, o[dt], 0, 0, 0);
    }
  }

#pragma unroll
  for (int r = 0; r < 4; ++r) {
    const float rinv = 1.0f / rsum[r];
    const int m = qw + l4 * 4 + r;
#pragma unroll
    for (int dt = 0; dt < 4; ++dt)
      att[(size_t)m * DM + h * DHEAD + dt * 16 + l15] = f2bf(o[dt][r] * rinv);
  }
}

// ---------------- launch ----------------
extern "C" void kernel_launch(void* const* d_in, const int* in_sizes, int n_in,
                              void* d_out, int out_size, void* d_ws, size_t ws_size,
                              hipStream_t stream) {
  const float* x    = (const float*)d_in[0];
  const float* wqkv = (const float*)d_in[1];
  const float* bqkv = (const float*)d_in[2];
  const float* wout = (const float*)d_in[3];
  const float* bout = (const float*)d_in[4];
  float* out = (float*)d_out;

  unsigned short* ws = (unsigned short*)d_ws;
  unsigned short* xb    = ws;
  unsigned short* wqkvb = xb    + (size_t)NSEQ * DM;
  unsigned short* woutb = wqkvb + (size_t)3 * DM * DM;
  unsigned short* qb    = woutb + (size_t)DM * DM;
  unsigned short* kb    = qb    + (size_t)NSEQ * DM;
  unsigned short* vtb   = kb    + (size_t)NSEQ * DM;
  unsigned short* attb  = vtb   + (size_t)NSEQ * DM;

  cvt_all<<<8192, 256, 0, stream>>>(x, wqkv, wout, xb);

  gemm_qkv<<<16 * 16, 512, 0, stream>>>(xb, wqkvb, bqkv, qb, kb, vtb);

  attn_kernel<<<NHEAD * (NSEQ / 64), 256, 0, stream>>>(qb, kb, vtb, attb);

  gemm_op<<<64 * 16, 256, 0, stream>>>(attb, woutb, bout, out);
}

// Round 13
// 80.178 us; speedup vs baseline: 1.0337x; 1.0150x over previous
//
#include <hip/hip_runtime.h>
#include <hip/hip_bf16.h>
#include <stdint.h>
#include <stddef.h>

#define NSEQ  4096
#define DM    1024
#define NHEAD 16
#define DHEAD 64
#define WIN   64

using short8 = __attribute__((ext_vector_type(8))) short;
using f32x4  = __attribute__((ext_vector_type(4))) float;

#define GLOBAL_AS __attribute__((address_space(1)))
#define LDS_AS    __attribute__((address_space(3)))

__device__ __forceinline__ unsigned short f2bf(float f) {
  union { float f; unsigned int u; } v; v.f = f;
  unsigned int r = v.u + 0x7FFFu + ((v.u >> 16) & 1u);
  return (unsigned short)(r >> 16);
}

__device__ __forceinline__ void gload_lds16(void* lds, const void* g) {
  __builtin_amdgcn_global_load_lds((const GLOBAL_AS unsigned int*)g,
                                   (LDS_AS unsigned int*)lds, 16, 0, 0);
}

// ---------------- fused fp32 -> bf16 conversion (x | w_qkv | w_out) --------
#define NX4 1048576
#define NW4 786432
__global__ void cvt_all(const float* __restrict__ x,
                        const float* __restrict__ wqkv,
                        const float* __restrict__ wout,
                        unsigned short* __restrict__ dst) {
  int i = blockIdx.x * blockDim.x + threadIdx.x;   // group of 4 floats
  float4 f;
  if (i < NX4)            f = ((const float4*)x)[i];
  else if (i < NX4 + NW4) f = ((const float4*)wqkv)[i - NX4];
  else                    f = ((const float4*)wout)[i - (NX4 + NW4)];
  ushort4 o;
  o.x = f2bf(f.x); o.y = f2bf(f.y); o.z = f2bf(f.z); o.w = f2bf(f.w);
  ((ushort4*)dst)[i] = o;
}

// ============ QKV GEMM: 256x192 tile, BK=64, batched 4-phase ===============
// REVERTED to the R6 ledger (5/5 validated: R5-R9). The R11 fine-grained
// ledger (1 pass / 1 fail) is condemned as the round-12 race suspect.
__global__ __launch_bounds__(512, 1)
void gemm_qkv(const unsigned short* __restrict__ A,
              const unsigned short* __restrict__ B,
              const float* __restrict__ bias,
              unsigned short* __restrict__ qo,
              unsigned short* __restrict__ ko,
              unsigned short* __restrict__ vo) {
  __shared__ short lds[57344];   // 112 KB: buf b at b*28672 {A:16384|B:12288}

  const int bm = blockIdx.x >> 4;    // M/256 = 16
  const int bn = blockIdx.x & 15;    // N/192 = 16
  const int m0 = bm << 8, n0 = bn * 192;
  const int tid = threadIdx.x, w = tid >> 6, l = tid & 63;
  const int wr = w >> 2, wc = w & 3;
  const int l15 = l & 15, l4 = l >> 4;
  const int srow = l >> 2;
  const int skel = ((l & 3) << 3) ^ ((l >= 32) << 4);          // inv-swz global k
  const int roff = l15 * 32 + ((l4 * 8) ^ ((l15 >= 8) * 16));  // swz read off

  f32x4 acc[8][3] = {};

  auto stageA = [&](int j, int qm) {
    const int base = (j & 1) * 28672 + qm * 8192;
#pragma unroll
    for (int r = 0; r < 2; ++r) {
      const int c = r * 8 + w;
      gload_lds16(&lds[base + c * 512 + l * 8],
                  A + (size_t)(m0 + qm * 128 + (c >> 1) * 16 + srow) * 1024
                    + (j << 6) + (c & 1) * 32 + skel);
    }
  };
  auto stageB = [&](int j, int qk) {
    const int base = (j & 1) * 28672 + 16384 + qk * 6144;
    {
      const int c = w;               // subtiles 0..7
      gload_lds16(&lds[base + c * 512 + l * 8],
                  B + (size_t)(n0 + c * 16 + srow) * 1024
                    + (j << 6) + qk * 32 + skel);
    }
    {
      const int c = 8 + (w & 3);     // subtiles 8..11 (x2 coverage)
      gload_lds16(&lds[base + c * 512 + l * 8],
                  B + (size_t)(n0 + c * 16 + srow) * 1024
                    + (j << 6) + qk * 32 + skel);
    }
  };

  // prologue: tile 0 complete + Bk0(1); vmcnt(2) leaves Bk0(1) in flight
  stageA(0, 0); stageA(0, 1); stageB(0, 1); stageB(0, 0); stageB(1, 0);
  asm volatile("s_waitcnt vmcnt(2)" ::: "memory");
  __builtin_amdgcn_s_barrier();

  const int NT = 16;   // 1024 / 64
  for (int j = 0; j < NT; ++j) {
    const int buf = (j & 1) * 28672;
    const short* Ah = &lds[buf + wr * 8192];
#pragma unroll
    for (int p = 0; p < 4; ++p) {
      const int qm = p & 1, qk = p >> 1;
      const short* Bh = &lds[buf + 16384 + qk * 6144];
      short8 af[4], bf[3];
#pragma unroll
      for (int i = 0; i < 4; ++i)
        af[i] = *(const short8*)&Ah[(qm * 4 + i) * 1024 + qk * 512 + roff];
#pragma unroll
      for (int ni = 0; ni < 3; ++ni)
        bf[ni] = *(const short8*)&Bh[(wc * 3 + ni) * 512 + roff];
      if (p == 0 && j + 1 < NT) { stageA(j + 1, 0); stageA(j + 1, 1); stageB(j + 1, 1); }
      if (p == 2 && j + 2 < NT) { stageB(j + 2, 0); }
      if (p == 3) {
        if (j + 2 < NT) asm volatile("s_waitcnt vmcnt(2)" ::: "memory");
        else            asm volatile("s_waitcnt vmcnt(0)" ::: "memory");
      } else {
        asm volatile("" ::: "memory");
      }
      __builtin_amdgcn_s_barrier();
      __builtin_amdgcn_s_setprio(1);
#pragma unroll
      for (int i = 0; i < 4; ++i)
#pragma unroll
        for (int ni = 0; ni < 3; ++ni)
          acc[qm * 4 + i][ni] = __builtin_amdgcn_mfma_f32_16x16x32_bf16(
              af[i], bf[ni], acc[qm * 4 + i][ni], 0, 0, 0);
      __builtin_amdgcn_s_setprio(0);
    }
  }

#pragma unroll
  for (int ni = 0; ni < 3; ++ni) {
    const int n  = n0 + wc * 48 + ni * 16 + l15;
    const float bv = bias[n];
    const int region = n >> 10;   // uniform per 16-col fragment
#pragma unroll
    for (int mi = 0; mi < 8; ++mi) {
      const int mb = m0 + wr * 128 + mi * 16 + l4 * 4;
      if (region == 0) {
        const int h = (n >> 6) & 15, d = n & 63;
#pragma unroll
        for (int r = 0; r < 4; ++r)
          qo[((size_t)(h * NSEQ + mb + r)) * DHEAD + d] =
              f2bf((acc[mi][ni][r] + bv) * 0.125f);
      } else if (region == 1) {
        const int nn = n - 1024;
        const int h = nn >> 6, d = nn & 63;
#pragma unroll
        for (int r = 0; r < 4; ++r)
          ko[((size_t)(h * NSEQ + mb + r)) * DHEAD + d] =
              f2bf(acc[mi][ni][r] + bv);
      } else {
        const int nn = n - 2048;    // = h*64 + d
        ushort4 pk;
        pk.x = f2bf(acc[mi][ni][0] + bv);
        pk.y = f2bf(acc[mi][ni][1] + bv);
        pk.z = f2bf(acc[mi][ni][2] + bv);
        pk.w = f2bf(acc[mi][ni][3] + bv);
        *(ushort4*)&vo[(size_t)nn * NSEQ + mb] = pk;   // V^T: [h*64+d][m]
      }
    }
  }
}

// ====== out-proj GEMM: 64x128 tile, BK=64, 2-buf, 2 blocks/CU ==============
// (kept from round 12 — controlled experiment: if the tripwire fires again,
// THIS kernel is the racer and reverts to the 3x-validated 64x64 next round)
__global__ __launch_bounds__(256)
void gemm_op(const unsigned short* __restrict__ A,
             const unsigned short* __restrict__ B,
             const float* __restrict__ bias,
             float* __restrict__ Cf) {
  __shared__ short lds[2][12288];   // 24 KB/buf: A 4096 | B 8192 shorts

  const int wg = (blockIdx.x & 7) * 64 + (blockIdx.x >> 3);  // XCD chunks
  const int bm = wg >> 3;           // 64 m-tiles (64 rows)
  const int bn = wg & 7;            // 8 n-tiles (128 cols)
  const int m0 = bm << 6, n0 = bn << 7;
  const int tid = threadIdx.x, w = tid >> 6, l = tid & 63;
  const int wr = w >> 1, wc = w & 1;
  const int l15 = l & 15, l4 = l >> 4;
  const int srow = l >> 2;
  const int skel = ((l & 3) << 3) ^ ((l >= 32) << 4);
  const int roff = l15 * 32 + ((l4 * 8) ^ ((l15 >= 8) * 16));

  f32x4 acc[2][4] = {};
  const int NT = 16;

  auto stage = [&](int t) {
    const int buf = t & 1;
    const int kb  = t << 6;
#pragma unroll
    for (int r = 0; r < 2; ++r) {          // A: 8 subtiles
      const int c = r * 4 + w;
      gload_lds16(&lds[buf][c * 512 + l * 8],
                  A + (size_t)(m0 + (c >> 1) * 16 + srow) * 1024
                    + kb + (c & 1) * 32 + skel);
    }
#pragma unroll
    for (int r = 0; r < 4; ++r) {          // B: 16 subtiles
      const int c = r * 4 + w;
      gload_lds16(&lds[buf][4096 + c * 512 + l * 8],
                  B + (size_t)(n0 + (c >> 1) * 16 + srow) * 1024
                    + kb + (c & 1) * 32 + skel);
    }
  };

  stage(0);
  for (int t = 0; t < NT; ++t) {
    __syncthreads();                    // full drain -> stage(t) visible
    if (t + 1 < NT) stage(t + 1);       // other buf (WAR-safe after barrier)
    const short* Ab = &lds[t & 1][0];
    const short* Bb = &lds[t & 1][4096];
    short8 af[2][2], bf[4][2];
#pragma unroll
    for (int mi = 0; mi < 2; ++mi)
#pragma unroll
      for (int kk = 0; kk < 2; ++kk)
        af[mi][kk] = *(const short8*)&Ab[((wr * 2 + mi) * 2 + kk) * 512 + roff];
#pragma unroll
    for (int ni = 0; ni < 4; ++ni)
#pragma unroll
      for (int kk = 0; kk < 2; ++kk)
        bf[ni][kk] = *(const short8*)&Bb[((wc * 4 + ni) * 2 + kk) * 512 + roff];
    __builtin_amdgcn_s_setprio(1);
#pragma unroll
    for (int kk = 0; kk < 2; ++kk)
#pragma unroll
      for (int mi = 0; mi < 2; ++mi)
#pragma unroll
        for (int ni = 0; ni < 4; ++ni)
          acc[mi][ni] = __builtin_amdgcn_mfma_f32_16x16x32_bf16(
              af[mi][kk], bf[ni][kk], acc[mi][ni], 0, 0, 0);
    __builtin_amdgcn_s_setprio(0);
  }

#pragma unroll
  for (int ni = 0; ni < 4; ++ni) {
    const int n  = n0 + wc * 64 + ni * 16 + l15;
    const float bv = bias[n];
#pragma unroll
    for (int mi = 0; mi < 2; ++mi) {
      const int mb = m0 + wr * 32 + mi * 16 + l4 * 4;
#pragma unroll
      for (int r = 0; r < 4; ++r)
        Cf[(size_t)(mb + r) * DM + n] = acc[mi][ni][r] + bv;
    }
  }
}

// ---------------- windowed causal attention: 6-tile window trim ------------
// (unchanged; validated R9-R11)
__global__ __launch_bounds__(256)
void attn_kernel(const unsigned short* __restrict__ Qb,
                 const unsigned short* __restrict__ Kb,
                 const unsigned short* __restrict__ Vt,
                 unsigned short* __restrict__ att) {
  __shared__ short Pl[4][16][136];
  const int h  = blockIdx.x >> 6;
  const int q0 = (blockIdx.x & 63) << 6;
  const int w  = threadIdx.x >> 6;
  const int l  = threadIdx.x & 63;
  const int l15 = l & 15, l4 = l >> 4;
  const int qw = q0 + w * 16;
  const int tb = w & ~1;

  const unsigned short* Qh = Qb + (size_t)h * NSEQ * DHEAD;
  const unsigned short* Kh = Kb + (size_t)h * NSEQ * DHEAD;
  const unsigned short* Vh = Vt + (size_t)h * DHEAD * NSEQ;

  short8 aq[2];
  {
    const int qrow = qw + l15;
    aq[0] = *(const short8*)&Qh[(size_t)qrow * DHEAD + l4 * 8];
    aq[1] = *(const short8*)&Qh[(size_t)qrow * DHEAD + 32 + l4 * 8];
  }

  f32x4 s[6] = {};
#pragma unroll
  for (int tt = 0; tt < 6; ++tt) {
    int j  = q0 - 64 + (tb + tt) * 16 + l15;
    int jc = j < 0 ? 0 : j;
    short8 b0 = *(const short8*)&Kh[(size_t)jc * DHEAD + l4 * 8];
    short8 b1 = *(const short8*)&Kh[(size_t)jc * DHEAD + 32 + l4 * 8];
    s[tt] = __builtin_amdgcn_mfma_f32_16x16x32_bf16(aq[0], b0, s[tt], 0, 0, 0);
    s[tt] = __builtin_amdgcn_mfma_f32_16x16x32_bf16(aq[1], b1, s[tt], 0, 0, 0);
  }

  float rmax[4] = {-3e38f, -3e38f, -3e38f, -3e38f};
#pragma unroll
  for (int tt = 0; tt < 6; ++tt)
#pragma unroll
    for (int r = 0; r < 4; ++r) {
      const int i = qw + l4 * 4 + r;
      const int j = q0 - 64 + (tb + tt) * 16 + l15;
      const int diff = i - j;
      float sv = (j >= 0 && diff >= 0 && diff < WIN) ? s[tt][r] : -3e38f;
      s[tt][r] = sv;
      rmax[r] = fmaxf(rmax[r], sv);
    }
#pragma unroll
  for (int r = 0; r < 4; ++r)
#pragma unroll
    for (int m = 1; m < 16; m <<= 1)
      rmax[r] = fmaxf(rmax[r], __shfl_xor(rmax[r], m, 64));

  float rsum[4] = {0.f, 0.f, 0.f, 0.f};
#pragma unroll
  for (int tt = 0; tt < 6; ++tt)
#pragma unroll
    for (int r = 0; r < 4; ++r) {
      float p = __expf(s[tt][r] - rmax[r]);
      s[tt][r] = p;
      rsum[r] += p;
    }
#pragma unroll
  for (int r = 0; r < 4; ++r)
#pragma unroll
    for (int m = 1; m < 16; m <<= 1)
      rsum[r] += __shfl_xor(rsum[r], m, 64);

#pragma unroll
  for (int tt = 0; tt < 6; ++tt)
#pragma unroll
    for (int r = 0; r < 4; ++r)
      Pl[w][l4 * 4 + r][(tb + tt) * 16 + l15] = (short)f2bf(s[tt][r]);

  f32x4 o[4] = {};
#pragma unroll
  for (int kq = 0; kq < 3; ++kq) {
    const int ks = (w >> 1) + kq;
    short8 ap = *(const short8*)&Pl[w][l15][ks * 32 + l4 * 8];
    int jg = q0 - 64 + ks * 32 + l4 * 8;
    if (jg < 0) jg = 0;
#pragma unroll
    for (int dt = 0; dt < 4; ++dt) {
      const int d = dt * 16 + l15;
      short8 bv = *(const short8*)&Vh[(size_t)d * NSEQ + jg];
      o[dt] = __builtin_amdgcn_mfma_f32_16x16x32_bf16(ap, bv, o[dt], 0, 0, 0);
    }
  }

#pragma unroll
  for (int r = 0; r < 4; ++r) {
    const float rinv = 1.0f / rsum[r];
    const int m = qw + l4 * 4 + r;
#pragma unroll
    for (int dt = 0; dt < 4; ++dt)
      att[(size_t)m * DM + h * DHEAD + dt * 16 + l15] = f2bf(o[dt][r] * rinv);
  }
}

// ---------------- launch ----------------
extern "C" void kernel_launch(void* const* d_in, const int* in_sizes, int n_in,
                              void* d_out, int out_size, void* d_ws, size_t ws_size,
                              hipStream_t stream) {
  const float* x    = (const float*)d_in[0];
  const float* wqkv = (const float*)d_in[1];
  const float* bqkv = (const float*)d_in[2];
  const float* wout = (const float*)d_in[3];
  const float* bout = (const float*)d_in[4];
  float* out = (float*)d_out;

  unsigned short* ws = (unsigned short*)d_ws;
  unsigned short* xb    = ws;
  unsigned short* wqkvb = xb    + (size_t)NSEQ * DM;
  unsigned short* woutb = wqkvb + (size_t)3 * DM * DM;
  unsigned short* qb    = woutb + (size_t)DM * DM;
  unsigned short* kb    = qb    + (size_t)NSEQ * DM;
  unsigned short* vtb   = kb    + (size_t)NSEQ * DM;
  unsigned short* attb  = vtb   + (size_t)NSEQ * DM;

  cvt_all<<<8192, 256, 0, stream>>>(x, wqkv, wout, xb);

  gemm_qkv<<<16 * 16, 512, 0, stream>>>(xb, wqkvb, bqkv, qb, kb, vtb);

  attn_kernel<<<NHEAD * (NSEQ / 64), 256, 0, stream>>>(qb, kb, vtb, attb);

  gemm_op<<<64 * 8, 256, 0, stream>>>(attb, woutb, bout, out);
}

// Round 14
// 79.447 us; speedup vs baseline: 1.0432x; 1.0092x over previous
//
#include <hip/hip_runtime.h>
#include <hip/hip_bf16.h>
#include <stdint.h>
#include <stddef.h>

#define NSEQ  4096
#define DM    1024
#define NHEAD 16
#define DHEAD 64
#define WIN   64

using short8 = __attribute__((ext_vector_type(8))) short;
using f32x4  = __attribute__((ext_vector_type(4))) float;

#define GLOBAL_AS __attribute__((address_space(1)))
#define LDS_AS    __attribute__((address_space(3)))

__device__ __forceinline__ unsigned short f2bf(float f) {
  union { float f; unsigned int u; } v; v.f = f;
  unsigned int r = v.u + 0x7FFFu + ((v.u >> 16) & 1u);
  return (unsigned short)(r >> 16);
}

__device__ __forceinline__ void gload_lds16(void* lds, const void* g) {
  __builtin_amdgcn_global_load_lds((const GLOBAL_AS unsigned int*)g,
                                   (LDS_AS unsigned int*)lds, 16, 0, 0);
}

// ---------------- fused fp32 -> bf16 conversion (x | w_qkv | w_out) --------
#define NX4 1048576
#define NW4 786432
__global__ void cvt_all(const float* __restrict__ x,
                        const float* __restrict__ wqkv,
                        const float* __restrict__ wout,
                        unsigned short* __restrict__ dst) {
  int i = blockIdx.x * blockDim.x + threadIdx.x;   // group of 4 floats
  float4 f;
  if (i < NX4)            f = ((const float4*)x)[i];
  else if (i < NX4 + NW4) f = ((const float4*)wqkv)[i - NX4];
  else                    f = ((const float4*)wout)[i - (NX4 + NW4)];
  ushort4 o;
  o.x = f2bf(f.x); o.y = f2bf(f.y); o.z = f2bf(f.z); o.w = f2bf(f.w);
  ((ushort4*)dst)[i] = o;
}

// ============ QKV GEMM: 128x384 tile, BK=64, 2-phase/tile, 24 MFMA/barrier =
// A[4096,1024], B[3072,1024] bf16 K-major. Grid 32x8 = 256 (1/CU, full fill).
// 8 waves (2M x 4N), per-wave C = 64x96 (acc[4][6]). LDS 128 KB = 2 bufs x
// {A: 16 subtiles (16 KB) | B: 2 k-slices x 24 subtiles (48 KB)}; 16x32
// subtiles, st_16x32 XOR swizzle (pre-swizzled global src, swizzled read).
// B = 24 subtiles = 3/thread exactly -> NO dup staging (vs R6's +25%).
// Per K-tile j, 2 phases qk=0/1, each {4 A-reads + 6 B-reads | stage |
// vmcnt? | barrier | setprio 24 MFMA} (validated R6 idiom, 6/6 record).
// Ledger (in-order VMEM queue): prologue {A0:2,Bk0(0):3,Bk1(0):3,Bk0(1):3},
// vmcnt(3) leaves Bk0(1). Steady: p0 stages {A(j+1):2, Bk1(j+1):3};
// p1 stages Bk0(j+2):3 then vmcnt(3) -> drains Bk0(j+1),A(j+1),Bk1(j+1).
// Tails: j=NT-2.p1 vmcnt(0); j=NT-1 none. WAR: stage targets buf whose last
// reads were issued >=1 barrier earlier (same separation as R6).
__global__ __launch_bounds__(512, 1)
void gemm_qkv(const unsigned short* __restrict__ A,
              const unsigned short* __restrict__ B,
              const float* __restrict__ bias,
              unsigned short* __restrict__ qo,
              unsigned short* __restrict__ ko,
              unsigned short* __restrict__ vo) {
  __shared__ short lds[65536];   // 128 KB: buf b at b*32768 {A:8192 | B:24576}

  const int bm = blockIdx.x >> 3;    // M/128 = 32
  const int bn = blockIdx.x & 7;     // N/384 = 8
  const int m0 = bm << 7, n0 = bn * 384;
  const int tid = threadIdx.x, w = tid >> 6, l = tid & 63;
  const int wr = w >> 2, wc = w & 3;
  const int l15 = l & 15, l4 = l >> 4;
  const int srow = l >> 2;
  const int skel = ((l & 3) << 3) ^ ((l >= 32) << 4);          // inv-swz global k
  const int roff = l15 * 32 + ((l4 * 8) ^ ((l15 >= 8) * 16));  // swz read off

  f32x4 acc[4][6] = {};

  auto stageA = [&](int j) {           // 16 subtiles c = rowblk*2 + ksl
    const int base = (j & 1) * 32768;
#pragma unroll
    for (int r = 0; r < 2; ++r) {
      const int c = r * 8 + w;
      gload_lds16(&lds[base + c * 512 + l * 8],
                  A + (size_t)(m0 + (c >> 1) * 16 + srow) * 1024
                    + (j << 6) + (c & 1) * 32 + skel);
    }
  };
  auto stageB = [&](int j, int qk) {   // 24 subtiles = 16-col groups, 3/thread
    const int base = (j & 1) * 32768 + 8192 + qk * 12288;
#pragma unroll
    for (int r = 0; r < 3; ++r) {
      const int c = r * 8 + w;
      gload_lds16(&lds[base + c * 512 + l * 8],
                  B + (size_t)(n0 + c * 16 + srow) * 1024
                    + (j << 6) + qk * 32 + skel);
    }
  };

  auto ldfrag = [&](short8* af, short8* bf, int buf, int qk) {
    const short* Ah = &lds[buf];
    const short* Bh = &lds[buf + 8192 + qk * 12288];
#pragma unroll
    for (int i = 0; i < 4; ++i)
      af[i] = *(const short8*)&Ah[((wr * 4 + i) * 2 + qk) * 512 + roff];
#pragma unroll
    for (int ni = 0; ni < 6; ++ni)
      bf[ni] = *(const short8*)&Bh[(wc * 6 + ni) * 512 + roff];
  };
  auto mfma24 = [&](const short8* af, const short8* bf) {
    __builtin_amdgcn_s_setprio(1);
#pragma unroll
    for (int i = 0; i < 4; ++i)
#pragma unroll
      for (int ni = 0; ni < 6; ++ni)
        acc[i][ni] = __builtin_amdgcn_mfma_f32_16x16x32_bf16(
            af[i], bf[ni], acc[i][ni], 0, 0, 0);
    __builtin_amdgcn_s_setprio(0);
  };

  // prologue
  stageA(0); stageB(0, 0); stageB(0, 1); stageB(1, 0);
  asm volatile("s_waitcnt vmcnt(3)" ::: "memory");   // Bk0(1) stays in flight
  __builtin_amdgcn_s_barrier();

  const int NT = 16;   // 1024 / 64
  short8 af[4], bf[6];
  for (int j = 0; j < NT; ++j) {
    const int buf = (j & 1) * 32768;
    // ---- p0 (qk=0) ----
    ldfrag(af, bf, buf, 0);
    if (j + 1 < NT) { stageA(j + 1); stageB(j + 1, 1); }
    __builtin_amdgcn_s_barrier();
    mfma24(af, bf);
    // ---- p1 (qk=1) ----
    ldfrag(af, bf, buf, 1);
    if (j + 2 < NT) {
      stageB(j + 2, 0);
      asm volatile("s_waitcnt vmcnt(3)" ::: "memory");  // {A,Bk1,Bk0}(j+1) in
    } else if (j + 1 < NT) {
      asm volatile("s_waitcnt vmcnt(0)" ::: "memory");
    }
    __builtin_amdgcn_s_barrier();
    mfma24(af, bf);
  }

  // epilogue: scatter to Q (scaled), K, V^T  (region per 16-col fragment)
#pragma unroll
  for (int ni = 0; ni < 6; ++ni) {
    const int n  = n0 + wc * 96 + ni * 16 + l15;
    const float bv = bias[n];
    const int region = n >> 10;
#pragma unroll
    for (int mi = 0; mi < 4; ++mi) {
      const int mb = m0 + wr * 64 + mi * 16 + l4 * 4;
      if (region == 0) {
        const int h = (n >> 6) & 15, d = n & 63;
#pragma unroll
        for (int r = 0; r < 4; ++r)
          qo[((size_t)(h * NSEQ + mb + r)) * DHEAD + d] =
              f2bf((acc[mi][ni][r] + bv) * 0.125f);
      } else if (region == 1) {
        const int nn = n - 1024;
        const int h = nn >> 6, d = nn & 63;
#pragma unroll
        for (int r = 0; r < 4; ++r)
          ko[((size_t)(h * NSEQ + mb + r)) * DHEAD + d] =
              f2bf(acc[mi][ni][r] + bv);
      } else {
        const int nn = n - 2048;    // = h*64 + d
        ushort4 pk;
        pk.x = f2bf(acc[mi][ni][0] + bv);
        pk.y = f2bf(acc[mi][ni][1] + bv);
        pk.z = f2bf(acc[mi][ni][2] + bv);
        pk.w = f2bf(acc[mi][ni][3] + bv);
        *(ushort4*)&vo[(size_t)nn * NSEQ + mb] = pk;   // V^T: [h*64+d][m]
      }
    }
  }
}

// ====== out-proj GEMM: 64x128 tile, BK=64, 2-buf, 2 blocks/CU ==============
// (unchanged from round 13 — validated pass)
__global__ __launch_bounds__(256)
void gemm_op(const unsigned short* __restrict__ A,
             const unsigned short* __restrict__ B,
             const float* __restrict__ bias,
             float* __restrict__ Cf) {
  __shared__ short lds[2][12288];   // 24 KB/buf: A 4096 | B 8192 shorts

  const int wg = (blockIdx.x & 7) * 64 + (blockIdx.x >> 3);  // XCD chunks
  const int bm = wg >> 3;           // 64 m-tiles (64 rows)
  const int bn = wg & 7;            // 8 n-tiles (128 cols)
  const int m0 = bm << 6, n0 = bn << 7;
  const int tid = threadIdx.x, w = tid >> 6, l = tid & 63;
  const int wr = w >> 1, wc = w & 1;
  const int l15 = l & 15, l4 = l >> 4;
  const int srow = l >> 2;
  const int skel = ((l & 3) << 3) ^ ((l >= 32) << 4);
  const int roff = l15 * 32 + ((l4 * 8) ^ ((l15 >= 8) * 16));

  f32x4 acc[2][4] = {};
  const int NT = 16;

  auto stage = [&](int t) {
    const int buf = t & 1;
    const int kb  = t << 6;
#pragma unroll
    for (int r = 0; r < 2; ++r) {          // A: 8 subtiles
      const int c = r * 4 + w;
      gload_lds16(&lds[buf][c * 512 + l * 8],
                  A + (size_t)(m0 + (c >> 1) * 16 + srow) * 1024
                    + kb + (c & 1) * 32 + skel);
    }
#pragma unroll
    for (int r = 0; r < 4; ++r) {          // B: 16 subtiles
      const int c = r * 4 + w;
      gload_lds16(&lds[buf][4096 + c * 512 + l * 8],
                  B + (size_t)(n0 + (c >> 1) * 16 + srow) * 1024
                    + kb + (c & 1) * 32 + skel);
    }
  };

  stage(0);
  for (int t = 0; t < NT; ++t) {
    __syncthreads();                    // full drain -> stage(t) visible
    if (t + 1 < NT) stage(t + 1);       // other buf (WAR-safe after barrier)
    const short* Ab = &lds[t & 1][0];
    const short* Bb = &lds[t & 1][4096];
    short8 af[2][2], bf[4][2];
#pragma unroll
    for (int mi = 0; mi < 2; ++mi)
#pragma unroll
      for (int kk = 0; kk < 2; ++kk)
        af[mi][kk] = *(const short8*)&Ab[((wr * 2 + mi) * 2 + kk) * 512 + roff];
#pragma unroll
    for (int ni = 0; ni < 4; ++ni)
#pragma unroll
      for (int kk = 0; kk < 2; ++kk)
        bf[ni][kk] = *(const short8*)&Bb[((wc * 4 + ni) * 2 + kk) * 512 + roff];
    __builtin_amdgcn_s_setprio(1);
#pragma unroll
    for (int kk = 0; kk < 2; ++kk)
#pragma unroll
      for (int mi = 0; mi < 2; ++mi)
#pragma unroll
        for (int ni = 0; ni < 4; ++ni)
          acc[mi][ni] = __builtin_amdgcn_mfma_f32_16x16x32_bf16(
              af[mi][kk], bf[ni][kk], acc[mi][ni], 0, 0, 0);
    __builtin_amdgcn_s_setprio(0);
  }

#pragma unroll
  for (int ni = 0; ni < 4; ++ni) {
    const int n  = n0 + wc * 64 + ni * 16 + l15;
    const float bv = bias[n];
#pragma unroll
    for (int mi = 0; mi < 2; ++mi) {
      const int mb = m0 + wr * 32 + mi * 16 + l4 * 4;
#pragma unroll
      for (int r = 0; r < 4; ++r)
        Cf[(size_t)(mb + r) * DM + n] = acc[mi][ni][r] + bv;
    }
  }
}

// ---------------- windowed causal attention: 6-tile window trim ------------
// (unchanged; validated R9-R13)
__global__ __launch_bounds__(256)
void attn_kernel(const unsigned short* __restrict__ Qb,
                 const unsigned short* __restrict__ Kb,
                 const unsigned short* __restrict__ Vt,
                 unsigned short* __restrict__ att) {
  __shared__ short Pl[4][16][136];
  const int h  = blockIdx.x >> 6;
  const int q0 = (blockIdx.x & 63) << 6;
  const int w  = threadIdx.x >> 6;
  const int l  = threadIdx.x & 63;
  const int l15 = l & 15, l4 = l >> 4;
  const int qw = q0 + w * 16;
  const int tb = w & ~1;

  const unsigned short* Qh = Qb + (size_t)h * NSEQ * DHEAD;
  const unsigned short* Kh = Kb + (size_t)h * NSEQ * DHEAD;
  const unsigned short* Vh = Vt + (size_t)h * DHEAD * NSEQ;

  short8 aq[2];
  {
    const int qrow = qw + l15;
    aq[0] = *(const short8*)&Qh[(size_t)qrow * DHEAD + l4 * 8];
    aq[1] = *(const short8*)&Qh[(size_t)qrow * DHEAD + 32 + l4 * 8];
  }

  f32x4 s[6] = {};
#pragma unroll
  for (int tt = 0; tt < 6; ++tt) {
    int j  = q0 - 64 + (tb + tt) * 16 + l15;
    int jc = j < 0 ? 0 : j;
    short8 b0 = *(const short8*)&Kh[(size_t)jc * DHEAD + l4 * 8];
    short8 b1 = *(const short8*)&Kh[(size_t)jc * DHEAD + 32 + l4 * 8];
    s[tt] = __builtin_amdgcn_mfma_f32_16x16x32_bf16(aq[0], b0, s[tt], 0, 0, 0);
    s[tt] = __builtin_amdgcn_mfma_f32_16x16x32_bf16(aq[1], b1, s[tt], 0, 0, 0);
  }

  float rmax[4] = {-3e38f, -3e38f, -3e38f, -3e38f};
#pragma unroll
  for (int tt = 0; tt < 6; ++tt)
#pragma unroll
    for (int r = 0; r < 4; ++r) {
      const int i = qw + l4 * 4 + r;
      const int j = q0 - 64 + (tb + tt) * 16 + l15;
      const int diff = i - j;
      float sv = (j >= 0 && diff >= 0 && diff < WIN) ? s[tt][r] : -3e38f;
      s[tt][r] = sv;
      rmax[r] = fmaxf(rmax[r], sv);
    }
#pragma unroll
  for (int r = 0; r < 4; ++r)
#pragma unroll
    for (int m = 1; m < 16; m <<= 1)
      rmax[r] = fmaxf(rmax[r], __shfl_xor(rmax[r], m, 64));

  float rsum[4] = {0.f, 0.f, 0.f, 0.f};
#pragma unroll
  for (int tt = 0; tt < 6; ++tt)
#pragma unroll
    for (int r = 0; r < 4; ++r) {
      float p = __expf(s[tt][r] - rmax[r]);
      s[tt][r] = p;
      rsum[r] += p;
    }
#pragma unroll
  for (int r = 0; r < 4; ++r)
#pragma unroll
    for (int m = 1; m < 16; m <<= 1)
      rsum[r] += __shfl_xor(rsum[r], m, 64);

#pragma unroll
  for (int tt = 0; tt < 6; ++tt)
#pragma unroll
    for (int r = 0; r < 4; ++r)
      Pl[w][l4 * 4 + r][(tb + tt) * 16 + l15] = (short)f2bf(s[tt][r]);

  f32x4 o[4] = {};
#pragma unroll
  for (int kq = 0; kq < 3; ++kq) {
    const int ks = (w >> 1) + kq;
    short8 ap = *(const short8*)&Pl[w][l15][ks * 32 + l4 * 8];
    int jg = q0 - 64 + ks * 32 + l4 * 8;
    if (jg < 0) jg = 0;
#pragma unroll
    for (int dt = 0; dt < 4; ++dt) {
      const int d = dt * 16 + l15;
      short8 bv = *(const short8*)&Vh[(size_t)d * NSEQ + jg];
      o[dt] = __builtin_amdgcn_mfma_f32_16x16x32_bf16(ap, bv, o[dt], 0, 0, 0);
    }
  }

#pragma unroll
  for (int r = 0; r < 4; ++r) {
    const float rinv = 1.0f / rsum[r];
    const int m = qw + l4 * 4 + r;
#pragma unroll
    for (int dt = 0; dt < 4; ++dt)
      att[(size_t)m * DM + h * DHEAD + dt * 16 + l15] = f2bf(o[dt][r] * rinv);
  }
}

// ---------------- launch ----------------
extern "C" void kernel_launch(void* const* d_in, const int* in_sizes, int n_in,
                              void* d_out, int out_size, void* d_ws, size_t ws_size,
                              hipStream_t stream) {
  const float* x    = (const float*)d_in[0];
  const float* wqkv = (const float*)d_in[1];
  const float* bqkv = (const float*)d_in[2];
  const float* wout = (const float*)d_in[3];
  const float* bout = (const float*)d_in[4];
  float* out = (float*)d_out;

  unsigned short* ws = (unsigned short*)d_ws;
  unsigned short* xb    = ws;
  unsigned short* wqkvb = xb    + (size_t)NSEQ * DM;
  unsigned short* woutb = wqkvb + (size_t)3 * DM * DM;
  unsigned short* qb    = woutb + (size_t)DM * DM;
  unsigned short* kb    = qb    + (size_t)NSEQ * DM;
  unsigned short* vtb   = kb    + (size_t)NSEQ * DM;
  unsigned short* attb  = vtb   + (size_t)NSEQ * DM;

  cvt_all<<<8192, 256, 0, stream>>>(x, wqkv, wout, xb);

  gemm_qkv<<<32 * 8, 512, 0, stream>>>(xb, wqkvb, bqkv, qb, kb, vtb);

  attn_kernel<<<NHEAD * (NSEQ / 64), 256, 0, stream>>>(qb, kb, vtb, attb);

  gemm_op<<<64 * 8, 256, 0, stream>>>(attb, woutb, bout, out);
}